// Round 13
// baseline (830.056 us; speedup 1.0000x reference)
//
#include <hip/hip_runtime.h>
#include <math.h>

#define BATCH 4
#define CIN 64
#define HW 256
#define NPIX 65536       // 256*256
#define OC 192
#define TH 294
#define NPIX_R 86436     // 294*294
#define PS2 49
#define NWIN 36          // 6*6 windows per batch
#define WCPB 2304        // window-channels per batch (36*64)
#define KSTR 52          // LDS row stride (208 B, 16B-aligned)

__device__ __forceinline__ float rl_f32(float v, int lane) {
    return __uint_as_float(__builtin_amdgcn_readlane(__float_as_uint(v), lane));
}

// ---------------- K1: 1x1 conv (qkv) as LDS-tiled GEMM ----------------------
__global__ __launch_bounds__(256)
void k_qkv1x1(const float* __restrict__ x, const float* __restrict__ w,
              float* __restrict__ A) {
    __shared__ float wT[64][64];     // wT[c][o]
    __shared__ float xs[64][256];    // xs[c][px]
    x += (size_t)blockIdx.z * CIN * NPIX;
    A += (size_t)blockIdx.z * OC * NPIX;
    const int tid = threadIdx.x;
    const int pxbase = blockIdx.x * 256;
    const int ocbase = blockIdx.y * 64;

    for (int idx = tid; idx < 1024; idx += 256) {
        int o = idx >> 4, c4 = idx & 15;
        float4 v = *reinterpret_cast<const float4*>(w + (size_t)(ocbase + o) * CIN + c4 * 4);
        wT[c4 * 4 + 0][o] = v.x; wT[c4 * 4 + 1][o] = v.y;
        wT[c4 * 4 + 2][o] = v.z; wT[c4 * 4 + 3][o] = v.w;
    }
    for (int idx = tid; idx < 4096; idx += 256) {
        int c = idx >> 6, p4 = idx & 63;
        float4 v = *reinterpret_cast<const float4*>(x + (size_t)c * NPIX + pxbase + p4 * 4);
        *reinterpret_cast<float4*>(&xs[c][p4 * 4]) = v;
    }
    __syncthreads();

    const int tx = tid & 15, ty = tid >> 4;
    float acc[4][16];
    #pragma unroll
    for (int a = 0; a < 4; ++a)
        #pragma unroll
        for (int b = 0; b < 16; ++b) acc[a][b] = 0.f;

    #pragma unroll 4
    for (int k = 0; k < 64; ++k) {
        float4 wv = *reinterpret_cast<const float4*>(&wT[k][ty * 4]);
        float wr[4] = {wv.x, wv.y, wv.z, wv.w};
        float xv[16];
        #pragma unroll
        for (int i = 0; i < 4; ++i) {
            float4 v = *reinterpret_cast<const float4*>(&xs[k][tx * 4 + i * 64]);
            xv[i * 4 + 0] = v.x; xv[i * 4 + 1] = v.y;
            xv[i * 4 + 2] = v.z; xv[i * 4 + 3] = v.w;
        }
        #pragma unroll
        for (int a = 0; a < 4; ++a)
            #pragma unroll
            for (int b = 0; b < 16; ++b)
                acc[a][b] = fmaf(wr[a], xv[b], acc[a][b]);
    }

    #pragma unroll
    for (int a = 0; a < 4; ++a) {
        float* Ap = A + (size_t)(ocbase + ty * 4 + a) * NPIX + pxbase;
        #pragma unroll
        for (int i = 0; i < 4; ++i)
            *reinterpret_cast<float4*>(Ap + tx * 4 + i * 64) =
                make_float4(acc[a][i * 4 + 0], acc[a][i * 4 + 1],
                            acc[a][i * 4 + 2], acc[a][i * 4 + 3]);
    }
}

// ---------------- K2: depthwise 3x3, 4 pixels/thread ------------------------
__global__ __launch_bounds__(256)
void k_dw3x3(const float* __restrict__ A, const float* __restrict__ dwv,
             float* __restrict__ Bf) {
    A  += (size_t)blockIdx.z * OC * NPIX;
    Bf += (size_t)blockIdx.z * OC * NPIX;
    int gid = blockIdx.x * 256 + threadIdx.x;
    int ch = gid >> 14;
    int q  = gid & 16383;
    int y  = q >> 6;
    int x4 = (q & 63) << 2;
    const float* Ap = A + (size_t)ch * NPIX;
    float wv[9];
    #pragma unroll
    for (int i = 0; i < 9; ++i) wv[i] = dwv[ch * 9 + i];
    float acc0 = 0.f, acc1 = 0.f, acc2 = 0.f, acc3 = 0.f;
    #pragma unroll
    for (int ky = 0; ky < 3; ++ky) {
        int yy = y + ky - 1;
        if (yy < 0 || yy >= HW) continue;
        const float* row = Ap + yy * HW;
        float cv[6];
        #pragma unroll
        for (int t = 0; t < 6; ++t) {
            int xx = x4 - 1 + t;
            cv[t] = (xx >= 0 && xx < HW) ? row[xx] : 0.f;
        }
        #pragma unroll
        for (int kx = 0; kx < 3; ++kx) {
            float wk = wv[ky * 3 + kx];
            acc0 = fmaf(cv[0 + kx], wk, acc0);
            acc1 = fmaf(cv[1 + kx], wk, acc1);
            acc2 = fmaf(cv[2 + kx], wk, acc2);
            acc3 = fmaf(cv[3 + kx], wk, acc3);
        }
    }
    *reinterpret_cast<float4*>(Bf + (size_t)ch * NPIX + y * HW + x4) =
        make_float4(acc0, acc1, acc2, acc3);
}

// ---------------- K3: block-per-wc attention, readlane broadcasts -----------
// Lane l holds K row l (kreg) + V col l (vcol) + its own inq/ink. Per row i:
// one lane-parallel ds_read of Q row, then v_readlane drives the dot; p stays
// in registers and v_readlane drives PV + ssum. No LDS broadcasts, no Ps/sums.
__global__ __launch_bounds__(256, 3)
void k_attn(const float* __restrict__ Bf, float* __restrict__ Cf) {
    __shared__ float Qs[PS2 * KSTR];
    __shared__ float Ks[PS2 * KSTR];
    __shared__ float Vs[PS2 * KSTR];
    Bf += (size_t)blockIdx.z * OC * NPIX;
    Cf += (size_t)blockIdx.z * (size_t)CIN * NPIX_R;
    const int tid = threadIdx.x;
    const int wv = tid >> 6, lane = tid & 63;
    const int wc  = blockIdx.x;                 // [0, 2304)
    const int ch  = wc & 63;
    const int win = wc >> 6;
    const int xw  = win / 6, yw = win - xw * 6;
    const float* qb = Bf + (size_t)ch * NPIX;
    const float* kb = qb + (size_t)64  * NPIX;
    const float* vb = qb + (size_t)128 * NPIX;
    const float scale = 255.0f / 293.0f;        // align_corners=True, 256->294

    // phase 1: bilinear gather into LDS with einops permutation
    for (int e = tid; e < PS2 * PS2; e += 256) {
        int rl = e / PS2;
        int cl = e - rl * PS2;
        int gy = xw * PS2 + rl, gx = yw * PS2 + cl;
        float sy = gy * scale, sx = gx * scale;
        int y0 = (int)sy, x0 = (int)sx;
        float ly = sy - y0, lx = sx - x0;
        int y1 = min(y0 + 1, HW - 1), x1 = min(x0 + 1, HW - 1);
        float w00 = (1.f - ly) * (1.f - lx), w01 = (1.f - ly) * lx;
        float w10 = ly * (1.f - lx),         w11 = ly * lx;
        int o00 = y0 * HW + x0, o01 = y0 * HW + x1;
        int o10 = y1 * HW + x0, o11 = y1 * HW + x1;
        int i = (cl / 7) * 7 + (rl % 7);
        int j = (cl % 7) * 7 + (rl / 7);
        int d = i * KSTR + j;
        Qs[d] = qb[o00] * w00 + qb[o01] * w01 + qb[o10] * w10 + qb[o11] * w11;
        Ks[d] = kb[o00] * w00 + kb[o01] * w01 + kb[o10] * w10 + kb[o11] * w11;
        Vs[d] = vb[o00] * w00 + vb[o01] * w01 + vb[o10] * w10 + vb[o11] * w11;
    }
    __syncthreads();

    const int l = min(lane, PS2 - 1);
    const bool act = (lane < PS2);

    // K row l -> registers; inverse norm lane-private
    float kreg[PS2];
    #pragma unroll
    for (int u = 0; u < 12; ++u) {
        float4 v = *reinterpret_cast<const float4*>(&Ks[l * KSTR + u * 4]);
        kreg[u * 4 + 0] = v.x; kreg[u * 4 + 1] = v.y;
        kreg[u * 4 + 2] = v.z; kreg[u * 4 + 3] = v.w;
    }
    kreg[48] = Ks[l * KSTR + 48];
    float kss = 0.f;
    #pragma unroll
    for (int t = 0; t < PS2; ++t) kss = fmaf(kreg[t], kreg[t], kss);
    const float inkl = 1.f / fmaxf(sqrtf(kss), 1e-12f);

    // V column l -> registers (lane-parallel, conflict-free)
    float vcol[PS2];
    #pragma unroll
    for (int jj = 0; jj < PS2; ++jj) vcol[jj] = Vs[jj * KSTR + l];

    // Q row l inverse norm -> lane register (broadcast later via readlane)
    float inql;
    {
        float qss = 0.f;
        #pragma unroll
        for (int u = 0; u < 12; ++u) {
            float4 v = *reinterpret_cast<const float4*>(&Qs[l * KSTR + u * 4]);
            qss = fmaf(v.x, v.x, qss); qss = fmaf(v.y, v.y, qss);
            qss = fmaf(v.z, v.z, qss); qss = fmaf(v.w, v.w, qss);
        }
        float q48 = Qs[l * KSTR + 48];
        qss = fmaf(q48, q48, qss);
        inql = 1.f / fmaxf(sqrtf(qss), 1e-12f);
    }

    // row loop: wave wv owns rows i = wv, wv+4, ...  (no barriers: row i is
    // read then overwritten only by its owner wave)
    const int l2 = min(lane, KSTR - 1);
    for (int i = wv; i < PS2; i += 4) {
        const float inq_i = rl_f32(inql, i);
        const float qv = Qs[i * KSTR + l2];     // lane-parallel single read

        float d0 = 0.f, d1 = 0.f, d2 = 0.f, d3 = 0.f;
        #pragma unroll
        for (int t = 0; t < 48; t += 4) {
            d0 = fmaf(rl_f32(qv, t + 0), kreg[t + 0], d0);
            d1 = fmaf(rl_f32(qv, t + 1), kreg[t + 1], d1);
            d2 = fmaf(rl_f32(qv, t + 2), kreg[t + 2], d2);
            d3 = fmaf(rl_f32(qv, t + 3), kreg[t + 3], d3);
        }
        d0 = fmaf(rl_f32(qv, 48), kreg[48], d0);
        float p = __expf(((d0 + d1) + (d2 + d3)) * inkl * inq_i);

        // PV + ssum via readlane of p (uniform values, no LDS)
        float o0 = 0.f, o1 = 0.f, o2 = 0.f, o3 = 0.f;
        float s0 = 0.f, s1 = 0.f, s2 = 0.f, s3 = 0.f;
        #pragma unroll
        for (int j = 0; j < 48; j += 4) {
            float p0 = rl_f32(p, j + 0), p1 = rl_f32(p, j + 1);
            float p2 = rl_f32(p, j + 2), p3 = rl_f32(p, j + 3);
            o0 = fmaf(p0, vcol[j + 0], o0); s0 += p0;
            o1 = fmaf(p1, vcol[j + 1], o1); s1 += p1;
            o2 = fmaf(p2, vcol[j + 2], o2); s2 += p2;
            o3 = fmaf(p3, vcol[j + 3], o3); s3 += p3;
        }
        float p48 = rl_f32(p, 48);
        o0 = fmaf(p48, vcol[48], o0); s0 += p48;
        float ot   = (o0 + o1) + (o2 + o3);
        float ssum = (s0 + s1) + (s2 + s3);
        if (act) Qs[i * KSTR + lane] = ot * (1.f / ssum);
    }
    __syncthreads();

    // epilogue: inverse window permutation via LDS -> spatial C (64,294,294)
    float* cb = Cf + (size_t)ch * NPIX_R;
    for (int e = tid; e < PS2 * PS2; e += 256) {
        int rl = e / PS2;
        int cl = e - rl * PS2;
        int i = (cl / 7) * 7 + (rl % 7);
        int j = (cl % 7) * 7 + (rl / 7);
        cb[(xw * PS2 + rl) * TH + (yw * PS2 + cl)] = Qs[i * KSTR + j];
    }
}

// ------- K4: bilinear down 294->256 + proj, reading SPATIAL C ---------------
__global__ __launch_bounds__(256)
void k_proj(const float* __restrict__ Cf, const float* __restrict__ pw,
            float* __restrict__ out) {
    Cf  += (size_t)blockIdx.z * (size_t)CIN * NPIX_R;
    out += (size_t)blockIdx.z * CIN * NPIX;
    int gid  = blockIdx.x * 256 + threadIdx.x;
    int half = gid >> 16;
    int p    = gid & 65535;
    int y = p >> 8, xx = p & 255;
    const float sc = 294.0f / 256.0f;
    float sy = fmaxf((y + 0.5f) * sc - 0.5f, 0.f);
    float sx = fmaxf((xx + 0.5f) * sc - 0.5f, 0.f);
    int y0 = (int)sy, x0 = (int)sx;
    float ly = sy - y0, lx = sx - x0;
    int y1 = min(y0 + 1, TH - 1), x1 = min(x0 + 1, TH - 1);
    float w00 = (1.f - ly) * (1.f - lx), w01 = (1.f - ly) * lx;
    float w10 = ly * (1.f - lx),         w11 = ly * lx;
    int o00 = y0 * TH + x0, o01 = y0 * TH + x1;
    int o10 = y1 * TH + x0, o11 = y1 * TH + x1;
    float rv[CIN];
    #pragma unroll
    for (int c = 0; c < CIN; ++c) {
        const float* cp = Cf + (size_t)c * NPIX_R;
        rv[c] = cp[o00] * w00 + cp[o01] * w01 + cp[o10] * w10 + cp[o11] * w11;
    }
    float* op = out + (size_t)half * 32 * NPIX + p;
    for (int o = 0; o < 32; ++o) {
        const float* wr = pw + (half * 32 + o) * CIN;
        float acc = 0.f;
        #pragma unroll
        for (int c = 0; c < CIN; ++c) acc = fmaf(rv[c], wr[c], acc);
        op[(size_t)o * NPIX] = acc;
    }
}

// ---------------- launch --------------------------------------------------
extern "C" void kernel_launch(void* const* d_in, const int* in_sizes, int n_in,
                              void* d_out, int out_size, void* d_ws, size_t ws_size,
                              hipStream_t stream) {
    const float* x   = (const float*)d_in[0];
    const float* qw  = (const float*)d_in[1];
    const float* dwv = (const float*)d_in[2];
    const float* pw  = (const float*)d_in[3];
    float* out = (float*)d_out;

    const size_t perAB = (size_t)OC * NPIX;
    const size_t needBig = (size_t)2 * BATCH * perAB * sizeof(float);  // 384 MB

    if (ws_size >= needBig) {
        float* A = (float*)d_ws;
        float* B = A + BATCH * perAB;
        float* C = A;   // spatial C (64,294,294)/batch = 22.1 MB aliases dead A
        hipLaunchKernelGGL(k_qkv1x1, dim3(256, 3, BATCH),   dim3(256), 0, stream, x, qw, A);
        hipLaunchKernelGGL(k_dw3x3,  dim3(12288, 1, BATCH), dim3(256), 0, stream, A, dwv, B);
        hipLaunchKernelGGL(k_attn,   dim3(WCPB, 1, BATCH),  dim3(256), 0, stream, B, C);
        hipLaunchKernelGGL(k_proj,   dim3(512, 1, BATCH),   dim3(256), 0, stream, C, pw, out);
    } else {
        float* A = (float*)d_ws;
        float* B = A + perAB;
        float* C = A;
        for (int b = 0; b < BATCH; ++b) {
            const float* xb = x + (size_t)b * CIN * NPIX;
            float* ob = out + (size_t)b * CIN * NPIX;
            hipLaunchKernelGGL(k_qkv1x1, dim3(256, 3, 1),   dim3(256), 0, stream, xb, qw, A);
            hipLaunchKernelGGL(k_dw3x3,  dim3(12288, 1, 1), dim3(256), 0, stream, A, dwv, B);
            hipLaunchKernelGGL(k_attn,   dim3(WCPB, 1, 1),  dim3(256), 0, stream, B, C);
            hipLaunchKernelGGL(k_proj,   dim3(512, 1, 1),   dim3(256), 0, stream, C, pw, ob);
        }
    }
}

// Round 14
// 703.144 us; speedup vs baseline: 1.1805x; 1.1805x over previous
//
#include <hip/hip_runtime.h>
#include <math.h>

#define BATCH 4
#define CIN 64
#define HW 256
#define NPIX 65536       // 256*256
#define OC 192
#define TH 294
#define NPIX_R 86436     // 294*294
#define PS2 49
#define NWIN 36          // 6*6 windows per batch
#define WCPB 2304        // window-channels per batch (36*64)
#define KSTR 52          // LDS row stride (208 B, 16B-aligned)

__device__ __forceinline__ float rl_f32(float v, int lane) {
    return __uint_as_float(__builtin_amdgcn_readlane(__float_as_uint(v), lane));
}

// ---------------- K1: 1x1 conv (qkv) as LDS-tiled GEMM ----------------------
__global__ __launch_bounds__(256)
void k_qkv1x1(const float* __restrict__ x, const float* __restrict__ w,
              float* __restrict__ A) {
    __shared__ float wT[64][64];     // wT[c][o]
    __shared__ float xs[64][256];    // xs[c][px]
    x += (size_t)blockIdx.z * CIN * NPIX;
    A += (size_t)blockIdx.z * OC * NPIX;
    const int tid = threadIdx.x;
    const int pxbase = blockIdx.x * 256;
    const int ocbase = blockIdx.y * 64;

    for (int idx = tid; idx < 1024; idx += 256) {
        int o = idx >> 4, c4 = idx & 15;
        float4 v = *reinterpret_cast<const float4*>(w + (size_t)(ocbase + o) * CIN + c4 * 4);
        wT[c4 * 4 + 0][o] = v.x; wT[c4 * 4 + 1][o] = v.y;
        wT[c4 * 4 + 2][o] = v.z; wT[c4 * 4 + 3][o] = v.w;
    }
    for (int idx = tid; idx < 4096; idx += 256) {
        int c = idx >> 6, p4 = idx & 63;
        float4 v = *reinterpret_cast<const float4*>(x + (size_t)c * NPIX + pxbase + p4 * 4);
        *reinterpret_cast<float4*>(&xs[c][p4 * 4]) = v;
    }
    __syncthreads();

    const int tx = tid & 15, ty = tid >> 4;
    float acc[4][16];
    #pragma unroll
    for (int a = 0; a < 4; ++a)
        #pragma unroll
        for (int b = 0; b < 16; ++b) acc[a][b] = 0.f;

    #pragma unroll 4
    for (int k = 0; k < 64; ++k) {
        float4 wv = *reinterpret_cast<const float4*>(&wT[k][ty * 4]);
        float wr[4] = {wv.x, wv.y, wv.z, wv.w};
        float xv[16];
        #pragma unroll
        for (int i = 0; i < 4; ++i) {
            float4 v = *reinterpret_cast<const float4*>(&xs[k][tx * 4 + i * 64]);
            xv[i * 4 + 0] = v.x; xv[i * 4 + 1] = v.y;
            xv[i * 4 + 2] = v.z; xv[i * 4 + 3] = v.w;
        }
        #pragma unroll
        for (int a = 0; a < 4; ++a)
            #pragma unroll
            for (int b = 0; b < 16; ++b)
                acc[a][b] = fmaf(wr[a], xv[b], acc[a][b]);
    }

    #pragma unroll
    for (int a = 0; a < 4; ++a) {
        float* Ap = A + (size_t)(ocbase + ty * 4 + a) * NPIX + pxbase;
        #pragma unroll
        for (int i = 0; i < 4; ++i)
            *reinterpret_cast<float4*>(Ap + tx * 4 + i * 64) =
                make_float4(acc[a][i * 4 + 0], acc[a][i * 4 + 1],
                            acc[a][i * 4 + 2], acc[a][i * 4 + 3]);
    }
}

// ---------------- K2: depthwise 3x3, 4 pixels/thread ------------------------
__global__ __launch_bounds__(256)
void k_dw3x3(const float* __restrict__ A, const float* __restrict__ dwv,
             float* __restrict__ Bf) {
    A  += (size_t)blockIdx.z * OC * NPIX;
    Bf += (size_t)blockIdx.z * OC * NPIX;
    int gid = blockIdx.x * 256 + threadIdx.x;
    int ch = gid >> 14;
    int q  = gid & 16383;
    int y  = q >> 6;
    int x4 = (q & 63) << 2;
    const float* Ap = A + (size_t)ch * NPIX;
    float wv[9];
    #pragma unroll
    for (int i = 0; i < 9; ++i) wv[i] = dwv[ch * 9 + i];
    float acc0 = 0.f, acc1 = 0.f, acc2 = 0.f, acc3 = 0.f;
    #pragma unroll
    for (int ky = 0; ky < 3; ++ky) {
        int yy = y + ky - 1;
        if (yy < 0 || yy >= HW) continue;
        const float* row = Ap + yy * HW;
        float cv[6];
        #pragma unroll
        for (int t = 0; t < 6; ++t) {
            int xx = x4 - 1 + t;
            cv[t] = (xx >= 0 && xx < HW) ? row[xx] : 0.f;
        }
        #pragma unroll
        for (int kx = 0; kx < 3; ++kx) {
            float wk = wv[ky * 3 + kx];
            acc0 = fmaf(cv[0 + kx], wk, acc0);
            acc1 = fmaf(cv[1 + kx], wk, acc1);
            acc2 = fmaf(cv[2 + kx], wk, acc2);
            acc3 = fmaf(cv[3 + kx], wk, acc3);
        }
    }
    *reinterpret_cast<float4*>(Bf + (size_t)ch * NPIX + y * HW + x4) =
        make_float4(acc0, acc1, acc2, acc3);
}

// ---------------- K3: block-per-wc attention, hybrid broadcasts -------------
// Lane l holds K row l + V col l in PINNED registers (asm keeps compiler from
// sinking them back to LDS). Per row i: Q via uniform LDS b128 (LDS pipe),
// p via exp (|S|<=1, no max shift), PV via readlane (VALU pipe); ssum via
// ones-column (lane 49) folded into PV, broadcast by one readlane.
#define PIN4(v) asm volatile("" : "+v"(v.x), "+v"(v.y), "+v"(v.z), "+v"(v.w))
#define SQ4(v) fmaf(v.x, v.x, fmaf(v.y, v.y, fmaf(v.z, v.z, v.w * v.w)))
#define DOT4(KV, OFS) { float4 q_ = *reinterpret_cast<const float4*>(qr + (OFS)); \
    dd0 = fmaf(q_.x, KV.x, dd0); dd1 = fmaf(q_.y, KV.y, dd1); \
    dd2 = fmaf(q_.z, KV.z, dd2); dd3 = fmaf(q_.w, KV.w, dd3); }
#define PV4(VV, J) { \
    o0 = fmaf(rl_f32(p, (J)+0), VV.x, o0); o1 = fmaf(rl_f32(p, (J)+1), VV.y, o1); \
    o2 = fmaf(rl_f32(p, (J)+2), VV.z, o2); o3 = fmaf(rl_f32(p, (J)+3), VV.w, o3); }
#define VC(jj) (act ? Vs[(jj) * KSTR + l] : 1.0f)

__global__ __launch_bounds__(256, 4)
void k_attn(const float* __restrict__ Bf, float* __restrict__ Cf) {
    __shared__ float Qs[PS2 * KSTR];
    __shared__ float Ks[PS2 * KSTR];
    __shared__ float Vs[PS2 * KSTR];
    Bf += (size_t)blockIdx.z * OC * NPIX;
    Cf += (size_t)blockIdx.z * (size_t)CIN * NPIX_R;
    const int tid = threadIdx.x;
    const int wv = tid >> 6, lane = tid & 63;
    const int wc  = blockIdx.x;                 // [0, 2304)
    const int ch  = wc & 63;
    const int win = wc >> 6;
    const int xw  = win / 6, yw = win - xw * 6;
    const float* qb = Bf + (size_t)ch * NPIX;
    const float* kb = qb + (size_t)64  * NPIX;
    const float* vb = qb + (size_t)128 * NPIX;
    const float scale = 255.0f / 293.0f;        // align_corners=True, 256->294

    // phase 1: bilinear gather into LDS with einops permutation
    for (int e = tid; e < PS2 * PS2; e += 256) {
        int rl = e / PS2;
        int cl = e - rl * PS2;
        int gy = xw * PS2 + rl, gx = yw * PS2 + cl;
        float sy = gy * scale, sx = gx * scale;
        int y0 = (int)sy, x0 = (int)sx;
        float ly = sy - y0, lx = sx - x0;
        int y1 = min(y0 + 1, HW - 1), x1 = min(x0 + 1, HW - 1);
        float w00 = (1.f - ly) * (1.f - lx), w01 = (1.f - ly) * lx;
        float w10 = ly * (1.f - lx),         w11 = ly * lx;
        int o00 = y0 * HW + x0, o01 = y0 * HW + x1;
        int o10 = y1 * HW + x0, o11 = y1 * HW + x1;
        int i = (cl / 7) * 7 + (rl % 7);
        int j = (cl % 7) * 7 + (rl / 7);
        int d = i * KSTR + j;
        Qs[d] = qb[o00] * w00 + qb[o01] * w01 + qb[o10] * w10 + qb[o11] * w11;
        Ks[d] = kb[o00] * w00 + kb[o01] * w01 + kb[o10] * w10 + kb[o11] * w11;
        Vs[d] = vb[o00] * w00 + vb[o01] * w01 + vb[o10] * w10 + vb[o11] * w11;
    }
    __syncthreads();

    const int l = min(lane, PS2 - 1);
    const bool act = (lane < PS2);

    // K row l -> named registers (pinned)
    const float* kr0 = &Ks[l * KSTR];
    float4 k0  = *reinterpret_cast<const float4*>(kr0 + 0);
    float4 k1  = *reinterpret_cast<const float4*>(kr0 + 4);
    float4 k2  = *reinterpret_cast<const float4*>(kr0 + 8);
    float4 k3  = *reinterpret_cast<const float4*>(kr0 + 12);
    float4 k4  = *reinterpret_cast<const float4*>(kr0 + 16);
    float4 k5  = *reinterpret_cast<const float4*>(kr0 + 20);
    float4 k6  = *reinterpret_cast<const float4*>(kr0 + 24);
    float4 k7  = *reinterpret_cast<const float4*>(kr0 + 28);
    float4 k8  = *reinterpret_cast<const float4*>(kr0 + 32);
    float4 k9  = *reinterpret_cast<const float4*>(kr0 + 36);
    float4 k10 = *reinterpret_cast<const float4*>(kr0 + 40);
    float4 k11 = *reinterpret_cast<const float4*>(kr0 + 44);
    float  k48 = kr0[48];
    PIN4(k0); PIN4(k1); PIN4(k2); PIN4(k3); PIN4(k4); PIN4(k5);
    PIN4(k6); PIN4(k7); PIN4(k8); PIN4(k9); PIN4(k10); PIN4(k11);

    float kss = SQ4(k0) + SQ4(k1) + SQ4(k2) + SQ4(k3) + SQ4(k4) + SQ4(k5)
              + SQ4(k6) + SQ4(k7) + SQ4(k8) + SQ4(k9) + SQ4(k10) + SQ4(k11)
              + k48 * k48;
    const float inkl = 1.f / fmaxf(sqrtf(kss), 1e-12f);

    // V column l -> named registers (pinned); lanes >= 49 get ones-column
    float4 v0  = make_float4(VC(0),  VC(1),  VC(2),  VC(3));
    float4 v1  = make_float4(VC(4),  VC(5),  VC(6),  VC(7));
    float4 v2  = make_float4(VC(8),  VC(9),  VC(10), VC(11));
    float4 v3  = make_float4(VC(12), VC(13), VC(14), VC(15));
    float4 v4  = make_float4(VC(16), VC(17), VC(18), VC(19));
    float4 v5  = make_float4(VC(20), VC(21), VC(22), VC(23));
    float4 v6  = make_float4(VC(24), VC(25), VC(26), VC(27));
    float4 v7  = make_float4(VC(28), VC(29), VC(30), VC(31));
    float4 v8  = make_float4(VC(32), VC(33), VC(34), VC(35));
    float4 v9  = make_float4(VC(36), VC(37), VC(38), VC(39));
    float4 v10 = make_float4(VC(40), VC(41), VC(42), VC(43));
    float4 v11 = make_float4(VC(44), VC(45), VC(46), VC(47));
    float  v48 = VC(48);
    PIN4(v0); PIN4(v1); PIN4(v2); PIN4(v3); PIN4(v4); PIN4(v5);
    PIN4(v6); PIN4(v7); PIN4(v8); PIN4(v9); PIN4(v10); PIN4(v11);
    asm volatile("" : "+v"(k48), "+v"(v48));

    // Q row l inverse norm (transient reads; value broadcast later by readlane)
    float inql;
    {
        const float* qrl = &Qs[l * KSTR];
        float qss = 0.f;
        #pragma unroll
        for (int u = 0; u < 12; ++u) {
            float4 t = *reinterpret_cast<const float4*>(qrl + u * 4);
            qss += SQ4(t);
        }
        float q48 = qrl[48];
        qss = fmaf(q48, q48, qss);
        inql = 1.f / fmaxf(sqrtf(qss), 1e-12f);
    }
    __syncthreads();   // all norm reads of Qs complete before any row write

    // row loop: wave wv owns rows i = wv, wv+4, ...
    for (int i = wv; i < PS2; i += 4) {
        const float inq_i = rl_f32(inql, i);
        const float* qr = &Qs[i * KSTR];        // uniform address -> broadcast
        float dd0 = 0.f, dd1 = 0.f, dd2 = 0.f, dd3 = 0.f;
        DOT4(k0, 0)   DOT4(k1, 4)   DOT4(k2, 8)   DOT4(k3, 12)
        DOT4(k4, 16)  DOT4(k5, 20)  DOT4(k6, 24)  DOT4(k7, 28)
        DOT4(k8, 32)  DOT4(k9, 36)  DOT4(k10, 40) DOT4(k11, 44)
        float dsum = (dd0 + dd1) + (dd2 + dd3);
        dsum = fmaf(qr[48], k48, dsum);
        float p = __expf(dsum * inkl * inq_i);

        float o0 = 0.f, o1 = 0.f, o2 = 0.f, o3 = 0.f;
        PV4(v0, 0)   PV4(v1, 4)   PV4(v2, 8)   PV4(v3, 12)
        PV4(v4, 16)  PV4(v5, 20)  PV4(v6, 24)  PV4(v7, 28)
        PV4(v8, 32)  PV4(v9, 36)  PV4(v10, 40) PV4(v11, 44)
        float ot = (o0 + o1) + (o2 + o3);
        ot = fmaf(rl_f32(p, 48), v48, ot);
        float ssum = rl_f32(ot, 49);            // ones-column result
        float res = ot * __builtin_amdgcn_rcpf(ssum);
        if (act) Qs[i * KSTR + lane] = res;     // row i owned by this wave
    }
    __syncthreads();

    // epilogue: inverse window permutation via LDS -> spatial C (64,294,294)
    float* cb = Cf + (size_t)ch * NPIX_R;
    for (int e = tid; e < PS2 * PS2; e += 256) {
        int rl = e / PS2;
        int cl = e - rl * PS2;
        int i = (cl / 7) * 7 + (rl % 7);
        int j = (cl % 7) * 7 + (rl / 7);
        cb[(xw * PS2 + rl) * TH + (yw * PS2 + cl)] = Qs[i * KSTR + j];
    }
}

// ------- K4: bilinear down 294->256 + proj, reading SPATIAL C ---------------
__global__ __launch_bounds__(256)
void k_proj(const float* __restrict__ Cf, const float* __restrict__ pw,
            float* __restrict__ out) {
    Cf  += (size_t)blockIdx.z * (size_t)CIN * NPIX_R;
    out += (size_t)blockIdx.z * CIN * NPIX;
    int gid  = blockIdx.x * 256 + threadIdx.x;
    int half = gid >> 16;
    int p    = gid & 65535;
    int y = p >> 8, xx = p & 255;
    const float sc = 294.0f / 256.0f;
    float sy = fmaxf((y + 0.5f) * sc - 0.5f, 0.f);
    float sx = fmaxf((xx + 0.5f) * sc - 0.5f, 0.f);
    int y0 = (int)sy, x0 = (int)sx;
    float ly = sy - y0, lx = sx - x0;
    int y1 = min(y0 + 1, TH - 1), x1 = min(x0 + 1, TH - 1);
    float w00 = (1.f - ly) * (1.f - lx), w01 = (1.f - ly) * lx;
    float w10 = ly * (1.f - lx),         w11 = ly * lx;
    int o00 = y0 * TH + x0, o01 = y0 * TH + x1;
    int o10 = y1 * TH + x0, o11 = y1 * TH + x1;
    float rv[CIN];
    #pragma unroll
    for (int c = 0; c < CIN; ++c) {
        const float* cp = Cf + (size_t)c * NPIX_R;
        rv[c] = cp[o00] * w00 + cp[o01] * w01 + cp[o10] * w10 + cp[o11] * w11;
    }
    float* op = out + (size_t)half * 32 * NPIX + p;
    for (int o = 0; o < 32; ++o) {
        const float* wr = pw + (half * 32 + o) * CIN;
        float acc = 0.f;
        #pragma unroll
        for (int c = 0; c < CIN; ++c) acc = fmaf(rv[c], wr[c], acc);
        op[(size_t)o * NPIX] = acc;
    }
}

// ---------------- launch --------------------------------------------------
extern "C" void kernel_launch(void* const* d_in, const int* in_sizes, int n_in,
                              void* d_out, int out_size, void* d_ws, size_t ws_size,
                              hipStream_t stream) {
    const float* x   = (const float*)d_in[0];
    const float* qw  = (const float*)d_in[1];
    const float* dwv = (const float*)d_in[2];
    const float* pw  = (const float*)d_in[3];
    float* out = (float*)d_out;

    const size_t perAB = (size_t)OC * NPIX;                            // floats
    const size_t needBig = (size_t)2 * BATCH * perAB * sizeof(float);  // ~402 MB
    const size_t needMid = (size_t)2 * 2 * perAB * sizeof(float);      // ~201 MB

    if (ws_size >= needBig) {
        float* A = (float*)d_ws;
        float* B = A + BATCH * perAB;
        float* C = A;   // spatial C (64,294,294)/batch aliases dead A
        hipLaunchKernelGGL(k_qkv1x1, dim3(256, 3, BATCH),   dim3(256), 0, stream, x, qw, A);
        hipLaunchKernelGGL(k_dw3x3,  dim3(12288, 1, BATCH), dim3(256), 0, stream, A, dwv, B);
        hipLaunchKernelGGL(k_attn,   dim3(WCPB, 1, BATCH),  dim3(256), 0, stream, B, C);
        hipLaunchKernelGGL(k_proj,   dim3(512, 1, BATCH),   dim3(256), 0, stream, C, pw, out);
    } else if (ws_size >= needMid) {
        float* A = (float*)d_ws;
        float* B = A + 2 * perAB;
        float* C = A;
        for (int b = 0; b < BATCH; b += 2) {
            const float* xb = x + (size_t)b * CIN * NPIX;
            float* ob = out + (size_t)b * CIN * NPIX;
            hipLaunchKernelGGL(k_qkv1x1, dim3(256, 3, 2),   dim3(256), 0, stream, xb, qw, A);
            hipLaunchKernelGGL(k_dw3x3,  dim3(12288, 1, 2), dim3(256), 0, stream, A, dwv, B);
            hipLaunchKernelGGL(k_attn,   dim3(WCPB, 1, 2),  dim3(256), 0, stream, B, C);
            hipLaunchKernelGGL(k_proj,   dim3(512, 1, 2),   dim3(256), 0, stream, C, pw, ob);
        }
    } else {
        float* A = (float*)d_ws;
        float* B = A + perAB;
        float* C = A;
        for (int b = 0; b < BATCH; ++b) {
            const float* xb = x + (size_t)b * CIN * NPIX;
            float* ob = out + (size_t)b * CIN * NPIX;
            hipLaunchKernelGGL(k_qkv1x1, dim3(256, 3, 1),   dim3(256), 0, stream, xb, qw, A);
            hipLaunchKernelGGL(k_dw3x3,  dim3(12288, 1, 1), dim3(256), 0, stream, A, dwv, B);
            hipLaunchKernelGGL(k_attn,   dim3(WCPB, 1, 1),  dim3(256), 0, stream, B, C);
            hipLaunchKernelGGL(k_proj,   dim3(512, 1, 1),   dim3(256), 0, stream, C, pw, ob);
        }
    }
}

// Round 15
// 553.731 us; speedup vs baseline: 1.4990x; 1.2698x over previous
//
#include <hip/hip_runtime.h>
#include <math.h>

#define BATCH 4
#define CIN 64
#define HW 256
#define NPIX 65536       // 256*256
#define OC 192
#define TH 294
#define NPIX_R 86436     // 294*294
#define PS2 49
#define NWIN 36          // 6*6 windows per batch
#define WCPB 2304        // window-channels per batch (36*64)
#define KSTR 52          // LDS row stride (208 B, 16B-aligned)

__device__ __forceinline__ float rl_f32(float v, int lane) {
    return __uint_as_float(__builtin_amdgcn_readlane(__float_as_uint(v), lane));
}

// ---------------- K1: 1x1 conv (qkv) as LDS-tiled GEMM ----------------------
__global__ __launch_bounds__(256)
void k_qkv1x1(const float* __restrict__ x, const float* __restrict__ w,
              float* __restrict__ A) {
    __shared__ float wT[64][64];     // wT[c][o]
    __shared__ float xs[64][256];    // xs[c][px]
    x += (size_t)blockIdx.z * CIN * NPIX;
    A += (size_t)blockIdx.z * OC * NPIX;
    const int tid = threadIdx.x;
    const int pxbase = blockIdx.x * 256;
    const int ocbase = blockIdx.y * 64;

    for (int idx = tid; idx < 1024; idx += 256) {
        int o = idx >> 4, c4 = idx & 15;
        float4 v = *reinterpret_cast<const float4*>(w + (size_t)(ocbase + o) * CIN + c4 * 4);
        wT[c4 * 4 + 0][o] = v.x; wT[c4 * 4 + 1][o] = v.y;
        wT[c4 * 4 + 2][o] = v.z; wT[c4 * 4 + 3][o] = v.w;
    }
    for (int idx = tid; idx < 4096; idx += 256) {
        int c = idx >> 6, p4 = idx & 63;
        float4 v = *reinterpret_cast<const float4*>(x + (size_t)c * NPIX + pxbase + p4 * 4);
        *reinterpret_cast<float4*>(&xs[c][p4 * 4]) = v;
    }
    __syncthreads();

    const int tx = tid & 15, ty = tid >> 4;
    float acc[4][16];
    #pragma unroll
    for (int a = 0; a < 4; ++a)
        #pragma unroll
        for (int b = 0; b < 16; ++b) acc[a][b] = 0.f;

    #pragma unroll 4
    for (int k = 0; k < 64; ++k) {
        float4 wv = *reinterpret_cast<const float4*>(&wT[k][ty * 4]);
        float wr[4] = {wv.x, wv.y, wv.z, wv.w};
        float xv[16];
        #pragma unroll
        for (int i = 0; i < 4; ++i) {
            float4 v = *reinterpret_cast<const float4*>(&xs[k][tx * 4 + i * 64]);
            xv[i * 4 + 0] = v.x; xv[i * 4 + 1] = v.y;
            xv[i * 4 + 2] = v.z; xv[i * 4 + 3] = v.w;
        }
        #pragma unroll
        for (int a = 0; a < 4; ++a)
            #pragma unroll
            for (int b = 0; b < 16; ++b)
                acc[a][b] = fmaf(wr[a], xv[b], acc[a][b]);
    }

    #pragma unroll
    for (int a = 0; a < 4; ++a) {
        float* Ap = A + (size_t)(ocbase + ty * 4 + a) * NPIX + pxbase;
        #pragma unroll
        for (int i = 0; i < 4; ++i)
            *reinterpret_cast<float4*>(Ap + tx * 4 + i * 64) =
                make_float4(acc[a][i * 4 + 0], acc[a][i * 4 + 1],
                            acc[a][i * 4 + 2], acc[a][i * 4 + 3]);
    }
}

// ---------------- K2: depthwise 3x3, 4 pixels/thread ------------------------
__global__ __launch_bounds__(256)
void k_dw3x3(const float* __restrict__ A, const float* __restrict__ dwv,
             float* __restrict__ Bf) {
    A  += (size_t)blockIdx.z * OC * NPIX;
    Bf += (size_t)blockIdx.z * OC * NPIX;
    int gid = blockIdx.x * 256 + threadIdx.x;
    int ch = gid >> 14;
    int q  = gid & 16383;
    int y  = q >> 6;
    int x4 = (q & 63) << 2;
    const float* Ap = A + (size_t)ch * NPIX;
    float wv[9];
    #pragma unroll
    for (int i = 0; i < 9; ++i) wv[i] = dwv[ch * 9 + i];
    float acc0 = 0.f, acc1 = 0.f, acc2 = 0.f, acc3 = 0.f;
    #pragma unroll
    for (int ky = 0; ky < 3; ++ky) {
        int yy = y + ky - 1;
        if (yy < 0 || yy >= HW) continue;
        const float* row = Ap + yy * HW;
        float cv[6];
        #pragma unroll
        for (int t = 0; t < 6; ++t) {
            int xx = x4 - 1 + t;
            cv[t] = (xx >= 0 && xx < HW) ? row[xx] : 0.f;
        }
        #pragma unroll
        for (int kx = 0; kx < 3; ++kx) {
            float wk = wv[ky * 3 + kx];
            acc0 = fmaf(cv[0 + kx], wk, acc0);
            acc1 = fmaf(cv[1 + kx], wk, acc1);
            acc2 = fmaf(cv[2 + kx], wk, acc2);
            acc3 = fmaf(cv[3 + kx], wk, acc3);
        }
    }
    *reinterpret_cast<float4*>(Bf + (size_t)ch * NPIX + y * HW + x4) =
        make_float4(acc0, acc1, acc2, acc3);
}

// ---------------- K3: block-per-wc attention, hybrid broadcasts -------------
#define PIN4(v) asm volatile("" : "+v"(v.x), "+v"(v.y), "+v"(v.z), "+v"(v.w))
#define SQ4(v) fmaf(v.x, v.x, fmaf(v.y, v.y, fmaf(v.z, v.z, v.w * v.w)))
#define DOT4(KV, OFS) { float4 q_ = *reinterpret_cast<const float4*>(qr + (OFS)); \
    dd0 = fmaf(q_.x, KV.x, dd0); dd1 = fmaf(q_.y, KV.y, dd1); \
    dd2 = fmaf(q_.z, KV.z, dd2); dd3 = fmaf(q_.w, KV.w, dd3); }
#define PV4(VV, J) { \
    o0 = fmaf(rl_f32(p, (J)+0), VV.x, o0); o1 = fmaf(rl_f32(p, (J)+1), VV.y, o1); \
    o2 = fmaf(rl_f32(p, (J)+2), VV.z, o2); o3 = fmaf(rl_f32(p, (J)+3), VV.w, o3); }
#define VC(jj) (act ? Vs[(jj) * KSTR + l] : 1.0f)

__global__ __launch_bounds__(256, 4)
void k_attn(const float* __restrict__ Bf, float* __restrict__ Cf) {
    __shared__ float Qs[PS2 * KSTR];
    __shared__ float Ks[PS2 * KSTR];
    __shared__ float Vs[PS2 * KSTR];
    Bf += (size_t)blockIdx.z * OC * NPIX;
    Cf += (size_t)blockIdx.z * (size_t)CIN * NPIX_R;
    const int tid = threadIdx.x;
    const int wv = tid >> 6, lane = tid & 63;
    const int wc  = blockIdx.x;                 // [0, 2304)
    const int ch  = wc & 63;
    const int win = wc >> 6;
    const int xw  = win / 6, yw = win - xw * 6;
    const float* qb = Bf + (size_t)ch * NPIX;
    const float* kb = qb + (size_t)64  * NPIX;
    const float* vb = qb + (size_t)128 * NPIX;
    const float scale = 255.0f / 293.0f;        // align_corners=True, 256->294

    for (int e = tid; e < PS2 * PS2; e += 256) {
        int rl = e / PS2;
        int cl = e - rl * PS2;
        int gy = xw * PS2 + rl, gx = yw * PS2 + cl;
        float sy = gy * scale, sx = gx * scale;
        int y0 = (int)sy, x0 = (int)sx;
        float ly = sy - y0, lx = sx - x0;
        int y1 = min(y0 + 1, HW - 1), x1 = min(x0 + 1, HW - 1);
        float w00 = (1.f - ly) * (1.f - lx), w01 = (1.f - ly) * lx;
        float w10 = ly * (1.f - lx),         w11 = ly * lx;
        int o00 = y0 * HW + x0, o01 = y0 * HW + x1;
        int o10 = y1 * HW + x0, o11 = y1 * HW + x1;
        int i = (cl / 7) * 7 + (rl % 7);
        int j = (cl % 7) * 7 + (rl / 7);
        int d = i * KSTR + j;
        Qs[d] = qb[o00] * w00 + qb[o01] * w01 + qb[o10] * w10 + qb[o11] * w11;
        Ks[d] = kb[o00] * w00 + kb[o01] * w01 + kb[o10] * w10 + kb[o11] * w11;
        Vs[d] = vb[o00] * w00 + vb[o01] * w01 + vb[o10] * w10 + vb[o11] * w11;
    }
    __syncthreads();

    const int l = min(lane, PS2 - 1);
    const bool act = (lane < PS2);

    const float* kr0 = &Ks[l * KSTR];
    float4 k0  = *reinterpret_cast<const float4*>(kr0 + 0);
    float4 k1  = *reinterpret_cast<const float4*>(kr0 + 4);
    float4 k2  = *reinterpret_cast<const float4*>(kr0 + 8);
    float4 k3  = *reinterpret_cast<const float4*>(kr0 + 12);
    float4 k4  = *reinterpret_cast<const float4*>(kr0 + 16);
    float4 k5  = *reinterpret_cast<const float4*>(kr0 + 20);
    float4 k6  = *reinterpret_cast<const float4*>(kr0 + 24);
    float4 k7  = *reinterpret_cast<const float4*>(kr0 + 28);
    float4 k8  = *reinterpret_cast<const float4*>(kr0 + 32);
    float4 k9  = *reinterpret_cast<const float4*>(kr0 + 36);
    float4 k10 = *reinterpret_cast<const float4*>(kr0 + 40);
    float4 k11 = *reinterpret_cast<const float4*>(kr0 + 44);
    float  k48 = kr0[48];
    PIN4(k0); PIN4(k1); PIN4(k2); PIN4(k3); PIN4(k4); PIN4(k5);
    PIN4(k6); PIN4(k7); PIN4(k8); PIN4(k9); PIN4(k10); PIN4(k11);

    float kss = SQ4(k0) + SQ4(k1) + SQ4(k2) + SQ4(k3) + SQ4(k4) + SQ4(k5)
              + SQ4(k6) + SQ4(k7) + SQ4(k8) + SQ4(k9) + SQ4(k10) + SQ4(k11)
              + k48 * k48;
    const float inkl = 1.f / fmaxf(sqrtf(kss), 1e-12f);

    float4 v0  = make_float4(VC(0),  VC(1),  VC(2),  VC(3));
    float4 v1  = make_float4(VC(4),  VC(5),  VC(6),  VC(7));
    float4 v2  = make_float4(VC(8),  VC(9),  VC(10), VC(11));
    float4 v3  = make_float4(VC(12), VC(13), VC(14), VC(15));
    float4 v4  = make_float4(VC(16), VC(17), VC(18), VC(19));
    float4 v5  = make_float4(VC(20), VC(21), VC(22), VC(23));
    float4 v6  = make_float4(VC(24), VC(25), VC(26), VC(27));
    float4 v7  = make_float4(VC(28), VC(29), VC(30), VC(31));
    float4 v8  = make_float4(VC(32), VC(33), VC(34), VC(35));
    float4 v9  = make_float4(VC(36), VC(37), VC(38), VC(39));
    float4 v10 = make_float4(VC(40), VC(41), VC(42), VC(43));
    float4 v11 = make_float4(VC(44), VC(45), VC(46), VC(47));
    float  v48 = VC(48);
    PIN4(v0); PIN4(v1); PIN4(v2); PIN4(v3); PIN4(v4); PIN4(v5);
    PIN4(v6); PIN4(v7); PIN4(v8); PIN4(v9); PIN4(v10); PIN4(v11);
    asm volatile("" : "+v"(k48), "+v"(v48));

    float inql;
    {
        const float* qrl = &Qs[l * KSTR];
        float qss = 0.f;
        #pragma unroll
        for (int u = 0; u < 12; ++u) {
            float4 t = *reinterpret_cast<const float4*>(qrl + u * 4);
            qss += SQ4(t);
        }
        float q48 = qrl[48];
        qss = fmaf(q48, q48, qss);
        inql = 1.f / fmaxf(sqrtf(qss), 1e-12f);
    }
    __syncthreads();   // all norm reads of Qs complete before any row write

    for (int i = wv; i < PS2; i += 4) {
        const float inq_i = rl_f32(inql, i);
        const float* qr = &Qs[i * KSTR];        // uniform address -> broadcast
        float dd0 = 0.f, dd1 = 0.f, dd2 = 0.f, dd3 = 0.f;
        DOT4(k0, 0)   DOT4(k1, 4)   DOT4(k2, 8)   DOT4(k3, 12)
        DOT4(k4, 16)  DOT4(k5, 20)  DOT4(k6, 24)  DOT4(k7, 28)
        DOT4(k8, 32)  DOT4(k9, 36)  DOT4(k10, 40) DOT4(k11, 44)
        float dsum = (dd0 + dd1) + (dd2 + dd3);
        dsum = fmaf(qr[48], k48, dsum);
        float p = __expf(dsum * inkl * inq_i);

        float o0 = 0.f, o1 = 0.f, o2 = 0.f, o3 = 0.f;
        PV4(v0, 0)   PV4(v1, 4)   PV4(v2, 8)   PV4(v3, 12)
        PV4(v4, 16)  PV4(v5, 20)  PV4(v6, 24)  PV4(v7, 28)
        PV4(v8, 32)  PV4(v9, 36)  PV4(v10, 40) PV4(v11, 44)
        float ot = (o0 + o1) + (o2 + o3);
        ot = fmaf(rl_f32(p, 48), v48, ot);
        float ssum = rl_f32(ot, 49);            // ones-column result
        float res = ot * __builtin_amdgcn_rcpf(ssum);
        if (act) Qs[i * KSTR + lane] = res;     // row i owned by this wave
    }
    __syncthreads();

    // epilogue: inverse window permutation via LDS -> spatial C (64,294,294)
    float* cb = Cf + (size_t)ch * NPIX_R;
    for (int e = tid; e < PS2 * PS2; e += 256) {
        int rl = e / PS2;
        int cl = e - rl * PS2;
        int i = (cl / 7) * 7 + (rl % 7);
        int j = (cl % 7) * 7 + (rl / 7);
        cb[(xw * PS2 + rl) * TH + (yw * PS2 + cl)] = Qs[i * KSTR + j];
    }
}

// ---------------- K4a: bilinear down 294->256, coalesced, 4 px/thread -------
__global__ __launch_bounds__(256)
void k_down(const float* __restrict__ Cf, float* __restrict__ D) {
    Cf += (size_t)blockIdx.z * (size_t)CIN * NPIX_R;
    D  += (size_t)blockIdx.z * (size_t)CIN * NPIX;
    int gid = blockIdx.x * 256 + threadIdx.x;   // ch*16384 + quad
    int ch = gid >> 14;                          // [0,64)
    int q  = gid & 16383;
    int y  = q >> 6;
    int x4 = (q & 63) << 2;
    const float sc = 294.0f / 256.0f;
    float sy = fmaxf((y + 0.5f) * sc - 0.5f, 0.f);
    int y0 = (int)sy;
    float ly = sy - y0;
    int y1 = min(y0 + 1, TH - 1);
    const float* r0 = Cf + (size_t)ch * NPIX_R + y0 * TH;
    const float* r1 = Cf + (size_t)ch * NPIX_R + y1 * TH;
    float res[4];
    #pragma unroll
    for (int t = 0; t < 4; ++t) {
        float sx = fmaxf((x4 + t + 0.5f) * sc - 0.5f, 0.f);
        int x0 = (int)sx;
        float lx = sx - x0;
        int x1 = min(x0 + 1, TH - 1);
        res[t] = (r0[x0] * (1.f - lx) + r0[x1] * lx) * (1.f - ly)
               + (r1[x0] * (1.f - lx) + r1[x1] * lx) * ly;
    }
    *reinterpret_cast<float4*>(D + (size_t)ch * NPIX + y * HW + x4) =
        make_float4(res[0], res[1], res[2], res[3]);
}

// ---------------- K4b: proj 1x1 conv as LDS-tiled GEMM (M=64) ---------------
__global__ __launch_bounds__(256)
void k_pmm(const float* __restrict__ D, const float* __restrict__ w,
           float* __restrict__ out) {
    __shared__ float wT[64][64];     // wT[c][o]
    __shared__ float xs[64][256];    // xs[c][px]
    D   += (size_t)blockIdx.z * CIN * NPIX;
    out += (size_t)blockIdx.z * CIN * NPIX;
    const int tid = threadIdx.x;
    const int pxbase = blockIdx.x * 256;

    for (int idx = tid; idx < 1024; idx += 256) {
        int o = idx >> 4, c4 = idx & 15;
        float4 v = *reinterpret_cast<const float4*>(w + (size_t)o * CIN + c4 * 4);
        wT[c4 * 4 + 0][o] = v.x; wT[c4 * 4 + 1][o] = v.y;
        wT[c4 * 4 + 2][o] = v.z; wT[c4 * 4 + 3][o] = v.w;
    }
    for (int idx = tid; idx < 4096; idx += 256) {
        int c = idx >> 6, p4 = idx & 63;
        float4 v = *reinterpret_cast<const float4*>(D + (size_t)c * NPIX + pxbase + p4 * 4);
        *reinterpret_cast<float4*>(&xs[c][p4 * 4]) = v;
    }
    __syncthreads();

    const int tx = tid & 15, ty = tid >> 4;
    float acc[4][16];
    #pragma unroll
    for (int a = 0; a < 4; ++a)
        #pragma unroll
        for (int b = 0; b < 16; ++b) acc[a][b] = 0.f;

    #pragma unroll 4
    for (int k = 0; k < 64; ++k) {
        float4 wv = *reinterpret_cast<const float4*>(&wT[k][ty * 4]);
        float wr[4] = {wv.x, wv.y, wv.z, wv.w};
        float xv[16];
        #pragma unroll
        for (int i = 0; i < 4; ++i) {
            float4 v = *reinterpret_cast<const float4*>(&xs[k][tx * 4 + i * 64]);
            xv[i * 4 + 0] = v.x; xv[i * 4 + 1] = v.y;
            xv[i * 4 + 2] = v.z; xv[i * 4 + 3] = v.w;
        }
        #pragma unroll
        for (int a = 0; a < 4; ++a)
            #pragma unroll
            for (int b = 0; b < 16; ++b)
                acc[a][b] = fmaf(wr[a], xv[b], acc[a][b]);
    }

    #pragma unroll
    for (int a = 0; a < 4; ++a) {
        float* op = out + (size_t)(ty * 4 + a) * NPIX + pxbase;
        #pragma unroll
        for (int i = 0; i < 4; ++i)
            *reinterpret_cast<float4*>(op + tx * 4 + i * 64) =
                make_float4(acc[a][i * 4 + 0], acc[a][i * 4 + 1],
                            acc[a][i * 4 + 2], acc[a][i * 4 + 3]);
    }
}

// ---------------- launch --------------------------------------------------
// ws per NB batches in flight: A region (NB*perAB floats) hosts, after A dies:
//   C spatial (NB * CIN*NPIX_R = NB*5.53M floats) then D (NB * CIN*NPIX =
//   NB*4.19M) -> 9.72M/batch < perAB (12.58M) -- fits in dead A.  B region
//   (NB*perAB) holds qkv post-dw.
extern "C" void kernel_launch(void* const* d_in, const int* in_sizes, int n_in,
                              void* d_out, int out_size, void* d_ws, size_t ws_size,
                              hipStream_t stream) {
    const float* x   = (const float*)d_in[0];
    const float* qw  = (const float*)d_in[1];
    const float* dwv = (const float*)d_in[2];
    const float* pw  = (const float*)d_in[3];
    float* out = (float*)d_out;

    const size_t perAB = (size_t)OC * NPIX;                            // floats
    const size_t needBig = (size_t)2 * BATCH * perAB * sizeof(float);  // ~402 MB
    const size_t needMid = (size_t)2 * 2 * perAB * sizeof(float);      // ~201 MB

    int NB;
    if (ws_size >= needBig)      NB = BATCH;
    else if (ws_size >= needMid) NB = 2;
    else                         NB = 1;

    float* A = (float*)d_ws;
    float* B = A + (size_t)NB * perAB;
    float* C = A;                                       // z-stride CIN*NPIX_R
    float* D = A + (size_t)NB * CIN * NPIX_R;           // z-stride CIN*NPIX

    for (int b = 0; b < BATCH; b += NB) {
        const float* xb = x + (size_t)b * CIN * NPIX;
        float* ob = out + (size_t)b * CIN * NPIX;
        hipLaunchKernelGGL(k_qkv1x1, dim3(256, 3, NB),   dim3(256), 0, stream, xb, qw, A);
        hipLaunchKernelGGL(k_dw3x3,  dim3(12288, 1, NB), dim3(256), 0, stream, A, dwv, B);
        hipLaunchKernelGGL(k_attn,   dim3(WCPB, 1, NB),  dim3(256), 0, stream, B, C);
        hipLaunchKernelGGL(k_down,   dim3(4096, 1, NB),  dim3(256), 0, stream, C, D);
        hipLaunchKernelGGL(k_pmm,    dim3(256, 1, NB),   dim3(256), 0, stream, D, pw, ob);
    }
}